// Round 1
// 395.284 us; speedup vs baseline: 1.0923x; 1.0923x over previous
//
#include <hip/hip_runtime.h>
#include <math.h>

// ---------------------------------------------------------------------------
// MultiHead_CrossAttention: out = (softmax_heads((y@Wq)·(x@Wkv_k)^T/8) @ Wkv_v) @ Wo
// B=4 L=4096 D=1024 H=16 hd=64.
// R4: GEMM ported from the 128² m97-structure (ceiling ~900 TF, was 29%
//     MfmaUtil) to the 256² 8-phase schedule: T2 K-split LDS XOR-swizzle,
//     T3+T4 counted vmcnt(4) (never drained to 0 in the loop), T5 setprio
//     around each 16-MFMA cluster, T1 XCD-chunked block swizzle.
// ---------------------------------------------------------------------------

typedef __attribute__((ext_vector_type(8))) short bf16x8;
typedef __attribute__((ext_vector_type(4))) float f32x4;

__device__ __forceinline__ float b2f(short s) {
    union { unsigned u; float f; } x;
    x.u = ((unsigned)(unsigned short)s) << 16;
    return x.f;
}
__device__ __forceinline__ short f2b(float f) {
    union { float f; unsigned u; } x;
    x.f = f;
    unsigned r = (x.u + 0x7FFFu + ((x.u >> 16) & 1u)) >> 16;  // RNE
    return (short)r;
}

// ---- cast fp32 -> bf16 for two tensors in one launch ----------------------
__global__ __launch_bounds__(256) void cast2_f32_bf16(
    const float* __restrict__ in0, short* __restrict__ out0,
    const float* __restrict__ in1, short* __restrict__ out1, int n) {
    int i = (blockIdx.x * 256 + threadIdx.x) * 4;
    const float* in = in0;
    short* out = out0;
    if (i >= n) {
        i -= n;
        in = in1;
        out = out1;
    }
    float4 v = *(const float4*)(in + i);
    short4 o;
    o.x = f2b(v.x); o.y = f2b(v.y); o.z = f2b(v.z); o.w = f2b(v.w);
    *(short4*)(out + i) = o;
}

// ---- transpose + cast: W[K][N] fp32 -> Wt[N][K] bf16 ----------------------
__global__ __launch_bounds__(256) void transpose_cast2(
    const float* __restrict__ W0, short* __restrict__ Wt0,
    const float* __restrict__ W1, short* __restrict__ Wt1, int K, int N) {
    const float* W = blockIdx.z ? W1 : W0;
    short* Wt = blockIdx.z ? Wt1 : Wt0;
    __shared__ float tile[32][33];
    int tx = threadIdx.x;
    int ty = threadIdx.y;
    int bx = blockIdx.x * 32;
    int by = blockIdx.y * 32;
#pragma unroll
    for (int j = 0; j < 32; j += 8)
        tile[ty + j][tx] = W[(size_t)(by + ty + j) * N + bx + tx];
    __syncthreads();
#pragma unroll
    for (int j = 0; j < 32; j += 8)
        Wt[(size_t)(bx + ty + j) * K + by + tx] = f2b(tile[tx][ty + j]);
}

// ---- bf16 MFMA GEMM, 256x256 tile, BK=64, 8-phase schedule ----------------
// 512 threads = 8 waves (2 row x 4 col), each wave owns a 128x64 C block as
// 8x4 grid of 16x16 frags. LDS: 2 buf x {A,B} x {k-half} x [256][32] bf16
// sub-tiles = 128 KiB. Swizzle: element (r,k) at slot (k>>3)^((r>>1)&3)
// within its 64 B row; global_load_lds writes linearly, so the *global*
// source column is pre-permuted per-thread (both-sides-or-neither, rule 21).
// Counted vmcnt(4) at phases 2 & 4: steady state keeps exactly 4 loads
// (next tile's k-half) in flight across every barrier.
#define BM 256
#define BN 256
#define BK 64

// sub-tile offset in shorts: [buf c][ab: 0=A 1=B][ks][256*32]
#define SUBOFF(c, ab, ks) (((((c) * 2 + (ab)) * 2 + (ks))) * 8192)

#define GLD16(g, l)                                           \
    __builtin_amdgcn_global_load_lds(                         \
        (const __attribute__((address_space(1))) void*)(g),   \
        (__attribute__((address_space(3))) void*)(l), 16, 0, 0)

#define STAGE_A(c, ks, kk)                                                   \
    do {                                                                     \
        GLD16(agp + (kk) + (ks) * 32, lbase + SUBOFF(c, 0, ks) * 2 + dst);   \
        GLD16(agp + (kk) + (ks) * 32 + qstep,                                \
              lbase + SUBOFF(c, 0, ks) * 2 + 8192 + dst);                    \
    } while (0)

#define STAGE_B(c, ks, kk)                                                   \
    do {                                                                     \
        GLD16(bgp + (kk) + (ks) * 32, lbase + SUBOFF(c, 1, ks) * 2 + dst);   \
        GLD16(bgp + (kk) + (ks) * 32 + qstep,                                \
              lbase + SUBOFF(c, 1, ks) * 2 + 8192 + dst);                    \
    } while (0)

// one phase's compute cluster: drain LDS reads, fence scheduling (rule 18),
// boost priority, 16 MFMAs on acc rows [MH, MH+4)
#define MFMA_CLUSTER(MH)                                                     \
    do {                                                                     \
        asm volatile("s_waitcnt lgkmcnt(0)" ::: "memory");                   \
        __builtin_amdgcn_sched_barrier(0);                                   \
        __builtin_amdgcn_s_setprio(1);                                       \
        _Pragma("unroll") for (int i_ = 0; i_ < 4; ++i_)                     \
            _Pragma("unroll") for (int j_ = 0; j_ < 4; ++j_)                 \
                acc[(MH) + i_][j_] = __builtin_amdgcn_mfma_f32_16x16x32_bf16(\
                    af[i_], bf[j_], acc[(MH) + i_][j_], 0, 0, 0);            \
        __builtin_amdgcn_s_setprio(0);                                       \
    } while (0)

template <int OUT_BF16>
__global__ __launch_bounds__(512, 2) void gemm_bt(
    const short* __restrict__ A,    // [M][K] bf16
    const short* __restrict__ Bt,   // [N][K] bf16 (pre-transposed weight)
    const float* __restrict__ bias, // [N]
    void* __restrict__ Cout,        // [M][N] bf16 or fp32
    int M, int N, int K) {
    __shared__ __align__(16) short lds[65536];  // 128 KiB

    const int tid = threadIdx.x;

    // T1: XCD-chunked swizzle (nwg % 8 == 0 for all our shapes)
    const int NX = gridDim.x;
    const int nwg = NX * gridDim.y;
    int lin = blockIdx.y * NX + blockIdx.x;
    lin = (lin & 7) * (nwg >> 3) + (lin >> 3);
    const int bn = (lin % NX) * BN;
    const int bm = (lin / NX) * BM;

    const int lane = tid & 63;
    const int wave = tid >> 6;
    const int wr = wave >> 2;  // 0..1: 128-row block
    const int wc = wave & 3;   // 0..3: 64-col block
    const int fr = lane & 15;
    const int kq = lane >> 4;
    // swizzled slot offset for frag reads (shorts): row low bits = fr
    const int rsw = (kq ^ ((fr >> 1) & 3)) << 3;
    const int aro = (wr * 128 + fr) * 32 + rsw;
    const int bro = (wc * 64 + fr) * 32 + rsw;

    // staging: thread tid covers sub-tile row (q*128 + tid/4), k-slot
    // (tid&3)^((tid>>3)&3) -- the inverse of the read swizzle
    const int srow = tid >> 2;
    const int sslot = ((tid & 3) ^ ((tid >> 3) & 3)) * 8;
    const short* agp = A + (size_t)(bm + srow) * K + sslot;
    const short* bgp = Bt + (size_t)(bn + srow) * K + sslot;
    const size_t qstep = (size_t)128 * K;
    char* const lbase = (char*)lds;
    const int dst = tid * 16;

    f32x4 acc[8][4];
#pragma unroll
    for (int i = 0; i < 8; ++i)
#pragma unroll
        for (int j = 0; j < 4; ++j) acc[i][j] = (f32x4){0.f, 0.f, 0.f, 0.f};

    // prologue: stage tile 0 (issue order fixes vmcnt semantics!)
    STAGE_A(0, 0, 0);
    STAGE_B(0, 0, 0);
    STAGE_A(0, 1, 0);
    STAGE_B(0, 1, 0);
    asm volatile("s_waitcnt vmcnt(4)" ::: "memory");  // k-half0 landed
    __builtin_amdgcn_s_barrier();

    const int NT = K >> 6;  // 16
    for (int t = 0; t < NT; ++t) {
        const int c = t & 1, cn = c ^ 1;
        // last iter: re-stage same tile (L2-hot) to keep vmcnt counts uniform
        const int knext = (t + 1 < NT ? t + 1 : t) << 6;
        bf16x8 af[4], bf[4];
        const short* la0 = &lds[SUBOFF(c, 0, 0) + aro];
        const short* lb0 = &lds[SUBOFF(c, 1, 0) + bro];
        // ---- phase 1: k-half0, mi 0-3 ----
#pragma unroll
        for (int i = 0; i < 4; ++i) af[i] = *(const bf16x8*)(la0 + i * 512);
#pragma unroll
        for (int j = 0; j < 4; ++j) bf[j] = *(const bf16x8*)(lb0 + j * 512);
        STAGE_A(cn, 0, knext);
        __builtin_amdgcn_sched_barrier(0);
        __builtin_amdgcn_s_barrier();
        MFMA_CLUSTER(0);
        __builtin_amdgcn_s_barrier();
        // ---- phase 2: k-half0, mi 4-7 ----
#pragma unroll
        for (int i = 0; i < 4; ++i)
            af[i] = *(const bf16x8*)(la0 + (4 + i) * 512);
        STAGE_B(cn, 0, knext);
        __builtin_amdgcn_sched_barrier(0);
        __builtin_amdgcn_s_barrier();
        MFMA_CLUSTER(4);
        // retire this tile's k-half1 (issued 2 phases back); 4 stay in flight
        asm volatile("s_waitcnt vmcnt(4)" ::: "memory");
        __builtin_amdgcn_s_barrier();
        // ---- phase 3: k-half1, mi 0-3 ----
        const short* la1 = &lds[SUBOFF(c, 0, 1) + aro];
        const short* lb1 = &lds[SUBOFF(c, 1, 1) + bro];
#pragma unroll
        for (int i = 0; i < 4; ++i) af[i] = *(const bf16x8*)(la1 + i * 512);
#pragma unroll
        for (int j = 0; j < 4; ++j) bf[j] = *(const bf16x8*)(lb1 + j * 512);
        STAGE_A(cn, 1, knext);
        __builtin_amdgcn_sched_barrier(0);
        __builtin_amdgcn_s_barrier();
        MFMA_CLUSTER(0);
        __builtin_amdgcn_s_barrier();
        // ---- phase 4: k-half1, mi 4-7 ----
#pragma unroll
        for (int i = 0; i < 4; ++i)
            af[i] = *(const bf16x8*)(la1 + (4 + i) * 512);
        STAGE_B(cn, 1, knext);
        __builtin_amdgcn_sched_barrier(0);
        __builtin_amdgcn_s_barrier();
        MFMA_CLUSTER(4);
        // retire next tile's k-half0; its k-half1 (4 loads) stays in flight
        asm volatile("s_waitcnt vmcnt(4)" ::: "memory");
        __builtin_amdgcn_s_barrier();
    }

    // epilogue: C row = bm + wr*128 + mi*16 + kq*4 + r, col = bn + wc*64 + ni*16 + fr
#pragma unroll
    for (int ni = 0; ni < 4; ++ni) {
        const int col = bn + wc * 64 + ni * 16 + fr;
        const float bv = bias[col];
#pragma unroll
        for (int mi = 0; mi < 8; ++mi) {
            const int row0 = bm + wr * 128 + mi * 16 + kq * 4;
#pragma unroll
            for (int r = 0; r < 4; ++r) {
                float v = acc[mi][ni][r] + bv;
                if (OUT_BF16)
                    ((short*)Cout)[(size_t)(row0 + r) * N + col] = f2b(v);
                else
                    ((float*)Cout)[(size_t)(row0 + r) * N + col] = v;
            }
        }
    }
    // drain the tail garbage-stage before LDS dealloc at wave exit
    asm volatile("s_waitcnt vmcnt(0)" ::: "memory");
}

// ---- attention over heads axis, one wave per position ---------------------
__global__ __launch_bounds__(256) void attn_kernel(
    const short* __restrict__ Q, const short* __restrict__ KV,
    short* __restrict__ VAL) {
    const int wave = threadIdx.x >> 6;
    const int lane = threadIdx.x & 63;
    const size_t p = (size_t)blockIdx.x * 4 + wave;
    const int dq = lane & 3;

    const bf16x8* qp = (const bf16x8*)(Q + p * 1024 + (size_t)lane * 16);
    bf16x8 q0 = qp[0], q1 = qp[1];
    float q[16];
#pragma unroll
    for (int j = 0; j < 8; ++j) {
        q[j] = b2f(q0[j]);
        q[8 + j] = b2f(q1[j]);
    }

    const short* kvb = KV + p * 2048;

    float s[16];
#pragma unroll
    for (int g = 0; g < 16; ++g) {
        const bf16x8* kp = (const bf16x8*)(kvb + g * 128 + dq * 16);
        bf16x8 k0 = kp[0], k1 = kp[1];
        float d = 0.f;
#pragma unroll
        for (int j = 0; j < 8; ++j) {
            d += q[j] * b2f(k0[j]);
            d += q[8 + j] * b2f(k1[j]);
        }
        s[g] = d;
    }
    float mx = -1e30f;
#pragma unroll
    for (int g = 0; g < 16; ++g) {
        s[g] += __shfl_xor(s[g], 1, 64);
        s[g] += __shfl_xor(s[g], 2, 64);
        s[g] *= 0.125f;
        mx = fmaxf(mx, s[g]);
    }
    float ssum = 0.f;
#pragma unroll
    for (int g = 0; g < 16; ++g) {
        s[g] = __expf(s[g] - mx);
        ssum += s[g];
    }
    const float inv = 1.0f / ssum;

    float vo[16];
#pragma unroll
    for (int j = 0; j < 16; ++j) vo[j] = 0.f;
#pragma unroll
    for (int g = 0; g < 16; ++g) {
        const float w = s[g] * inv;
        const bf16x8* vp = (const bf16x8*)(kvb + g * 128 + 64 + dq * 16);
        bf16x8 v0 = vp[0], v1 = vp[1];
#pragma unroll
        for (int j = 0; j < 8; ++j) {
            vo[j] += w * b2f(v0[j]);
            vo[8 + j] += w * b2f(v1[j]);
        }
    }

    bf16x8 o0, o1;
#pragma unroll
    for (int j = 0; j < 8; ++j) {
        o0[j] = f2b(vo[j]);
        o1[j] = f2b(vo[8 + j]);
    }
    bf16x8* op = (bf16x8*)(VAL + p * 1024 + (size_t)lane * 16);
    op[0] = o0;
    op[1] = o1;
}

// ---------------------------------------------------------------------------
extern "C" void kernel_launch(void* const* d_in, const int* in_sizes, int n_in,
                              void* d_out, int out_size, void* d_ws,
                              size_t ws_size, hipStream_t stream) {
    const float* x = (const float*)d_in[0];
    const float* y = (const float*)d_in[1];
    const float* Wkv = (const float*)d_in[2];
    const float* bkv = (const float*)d_in[3];
    const float* Wq = (const float*)d_in[4];
    const float* bq = (const float*)d_in[5];
    const float* Wo = (const float*)d_in[6];
    const float* bo = (const float*)d_in[7];
    float* out = (float*)d_out;

    const int D = 1024;
    const int M = 16384;  // B*L

    // workspace layout (142.6 MB total)
    char* ws = (char*)d_ws;
    short* Xb = (short*)(ws);                      // M*D bf16      (33.5 MB)
    short* Yb = (short*)(ws + 33554432);           // M*D bf16      (33.5 MB)
    short* Wkvt = (short*)(ws + 67108864);         // 2D*D bf16     (4 MB)
    short* Wqt = (short*)(ws + 71303168);          // D*D bf16      (2 MB)
    short* Wot = (short*)(ws + 73400320);          // D*D bf16      (2 MB)
    short* KV = (short*)(ws + 75497472);           // M*2D bf16     (67 MB)
    short* Q = Xb;    // Xb dead after kv GEMM
    short* VAL = Yb;  // Yb dead after q GEMM

    const int n = M * D;  // 16777216

    cast2_f32_bf16<<<2 * n / 1024, 256, 0, stream>>>(x, Xb, y, Yb, n);
    transpose_cast2<<<dim3(2 * D / 32, D / 32, 1), dim3(32, 8), 0, stream>>>(
        Wkv, Wkvt, (const float*)0, (short*)0, D, 2 * D);
    transpose_cast2<<<dim3(D / 32, D / 32, 2), dim3(32, 8), 0, stream>>>(
        Wq, Wqt, Wo, Wot, D, D);

    // kv = x @ Wkv + bkv   [16384 x 2048] bf16
    gemm_bt<1><<<dim3(2 * D / BN, M / BM), 512, 0, stream>>>(
        Xb, Wkvt, bkv, KV, M, 2 * D, D);
    // q = y @ Wq + bq      [16384 x 1024] bf16 (into Xb slot)
    gemm_bt<1><<<dim3(D / BN, M / BM), 512, 0, stream>>>(
        Yb, Wqt, bq, Q, M, D, D);
    // attention over heads -> VAL (into Yb slot)
    attn_kernel<<<M / 4, 256, 0, stream>>>(Q, KV, VAL);
    // out = val @ Wo + bo  [16384 x 1024] fp32
    gemm_bt<0><<<dim3(D / BN, M / BM), 512, 0, stream>>>(
        VAL, Wot, bo, out, M, D, D);
}

// Round 2
// 373.575 us; speedup vs baseline: 1.1558x; 1.0581x over previous
//
#include <hip/hip_runtime.h>
#include <math.h>

// ---------------------------------------------------------------------------
// MultiHead_CrossAttention: out = (softmax_heads((y@Wq)·(x@Wkv_k)^T/8) @ Wkv_v) @ Wo
// B=4 L=4096 D=1024 H=16 hd=64.
// R5: GEMM K-pipeline rebuilt as a 4-slot ring of K-halves (BK/2=32):
//     pair m consumes slot m&3, issues half m+3 (distance 4-5 phases vs 2-3
//     before -> vmcnt(8) never stalls on HBM latency), single counted wait
//     per pair. Epilogue reordered ni-inner to fill cache lines with
//     consecutive stores (round-1 WRITE_SIZE was 1.73x output).
// ---------------------------------------------------------------------------

typedef __attribute__((ext_vector_type(8))) short bf16x8;
typedef __attribute__((ext_vector_type(4))) float f32x4;

__device__ __forceinline__ float b2f(short s) {
    union { unsigned u; float f; } x;
    x.u = ((unsigned)(unsigned short)s) << 16;
    return x.f;
}
__device__ __forceinline__ short f2b(float f) {
    union { float f; unsigned u; } x;
    x.f = f;
    unsigned r = (x.u + 0x7FFFu + ((x.u >> 16) & 1u)) >> 16;  // RNE
    return (short)r;
}

// ---- cast fp32 -> bf16 for two tensors in one launch ----------------------
__global__ __launch_bounds__(256) void cast2_f32_bf16(
    const float* __restrict__ in0, short* __restrict__ out0,
    const float* __restrict__ in1, short* __restrict__ out1, int n) {
    int i = (blockIdx.x * 256 + threadIdx.x) * 4;
    const float* in = in0;
    short* out = out0;
    if (i >= n) {
        i -= n;
        in = in1;
        out = out1;
    }
    float4 v = *(const float4*)(in + i);
    short4 o;
    o.x = f2b(v.x); o.y = f2b(v.y); o.z = f2b(v.z); o.w = f2b(v.w);
    *(short4*)(out + i) = o;
}

// ---- transpose + cast: W[K][N] fp32 -> Wt[N][K] bf16 ----------------------
__global__ __launch_bounds__(256) void transpose_cast2(
    const float* __restrict__ W0, short* __restrict__ Wt0,
    const float* __restrict__ W1, short* __restrict__ Wt1, int K, int N) {
    const float* W = blockIdx.z ? W1 : W0;
    short* Wt = blockIdx.z ? Wt1 : Wt0;
    __shared__ float tile[32][33];
    int tx = threadIdx.x;
    int ty = threadIdx.y;
    int bx = blockIdx.x * 32;
    int by = blockIdx.y * 32;
#pragma unroll
    for (int j = 0; j < 32; j += 8)
        tile[ty + j][tx] = W[(size_t)(by + ty + j) * N + bx + tx];
    __syncthreads();
#pragma unroll
    for (int j = 0; j < 32; j += 8)
        Wt[(size_t)(bx + ty + j) * K + by + tx] = f2b(tile[tx][ty + j]);
}

// ---- bf16 MFMA GEMM, 256x256 tile, 4-slot K-half ring ---------------------
// 512 threads = 8 waves (2 row x 4 col), each wave owns a 128x64 C block as
// 8x4 grid of 16x16 frags. LDS: 4 slots x (A[256][32] + B[256][32]) bf16 =
// 128 KiB. Slot s holds K-half m (m&3==s, 32 k-cols). Pair m = 2 phases
// (mi 0-3, mi 4-7), 16 MFMA each. During pair m we issue half m+3's loads
// (A in phase A, B in phase B) and retire half m+1 with vmcnt(8) at pair
// end -- issue->wait distance 4-5 phases, 12 loads in flight, never drained.
// Swizzle (both sides, rule 21): element (r, kchunk) of a half lives at
// 16B-slot kchunk^((r>>1)&3) within its 64 B row; realized by pre-permuted
// global source column (staging) + XOR'd ds_read address (reads).
#define BM 256
#define BN 256

#define GLD16(g, l)                                           \
    __builtin_amdgcn_global_load_lds(                         \
        (const __attribute__((address_space(1))) void*)(g),   \
        (__attribute__((address_space(3))) void*)(l), 16, 0, 0)

// one phase's compute cluster: drain LDS reads, fence scheduling (rule 18),
// boost priority, 16 MFMAs on acc rows [MH, MH+4)
#define MFMA_CLUSTER(MH)                                                     \
    do {                                                                     \
        asm volatile("s_waitcnt lgkmcnt(0)" ::: "memory");                   \
        __builtin_amdgcn_sched_barrier(0);                                   \
        __builtin_amdgcn_s_setprio(1);                                       \
        _Pragma("unroll") for (int i_ = 0; i_ < 4; ++i_)                     \
            _Pragma("unroll") for (int j_ = 0; j_ < 4; ++j_)                 \
                acc[(MH) + i_][j_] = __builtin_amdgcn_mfma_f32_16x16x32_bf16(\
                    af[i_], bfr[j_], acc[(MH) + i_][j_], 0, 0, 0);           \
        __builtin_amdgcn_s_setprio(0);                                       \
    } while (0)

template <int OUT_BF16>
__global__ __launch_bounds__(512, 2) void gemm_bt(
    const short* __restrict__ A,    // [M][K] bf16
    const short* __restrict__ Bt,   // [N][K] bf16 (pre-transposed weight)
    const float* __restrict__ bias, // [N]
    void* __restrict__ Cout,        // [M][N] bf16 or fp32
    int M, int N, int K) {
    __shared__ __align__(16) short lds[65536];  // 128 KiB

    const int tid = threadIdx.x;

    // T1: XCD-chunked swizzle (nwg % 8 == 0 for all our shapes)
    const int NX = gridDim.x;
    const int nwg = NX * gridDim.y;
    int lin = blockIdx.y * NX + blockIdx.x;
    lin = (lin & 7) * (nwg >> 3) + (lin >> 3);
    const int bn = (lin % NX) * BN;
    const int bm = (lin / NX) * BM;

    const int lane = tid & 63;
    const int wave = tid >> 6;
    const int wr = wave >> 2;  // 0..1: 128-row block
    const int wc = wave & 3;   // 0..3: 64-col block
    const int fr = lane & 15;
    const int kq = lane >> 4;
    // swizzled 16B-slot offset for frag reads (shorts)
    const int rsw = (kq ^ ((fr >> 1) & 3)) << 3;
    const int aro = (wr * 128 + fr) * 32 + rsw;
    const int bro = (wc * 64 + fr) * 32 + rsw;

    // staging: thread tid covers row tid/4 (and +128), 16B-slot tid&3;
    // source k-chunk = (tid&3)^((tid>>3)&3) (inverse of read swizzle)
    const int srow = tid >> 2;
    const int sslot = ((tid & 3) ^ ((tid >> 3) & 3)) * 8;
    const short* agp = A + (size_t)(bm + srow) * K + sslot;
    const short* bgp = Bt + (size_t)(bn + srow) * K + sslot;
    const size_t qstep = (size_t)128 * K;
    char* const lbase = (char*)lds;
    const int dst = tid * 16;

    f32x4 acc[8][4];
#pragma unroll
    for (int i = 0; i < 8; ++i)
#pragma unroll
        for (int j = 0; j < 4; ++j) acc[i][j] = (f32x4){0.f, 0.f, 0.f, 0.f};

    // prologue: issue halves 0,1,2 (12 loads, oldest-first)
#pragma unroll
    for (int h = 0; h < 3; ++h) {
        const int kk = h << 5;
        GLD16(agp + kk, lbase + h * 32768 + dst);
        GLD16(agp + kk + qstep, lbase + h * 32768 + 8192 + dst);
        GLD16(bgp + kk, lbase + h * 32768 + 16384 + dst);
        GLD16(bgp + kk + qstep, lbase + h * 32768 + 24576 + dst);
    }
    asm volatile("s_waitcnt vmcnt(8)" ::: "memory");  // half 0 landed
    __builtin_amdgcn_s_barrier();

    const int NH = K >> 5;  // 32 K-halves
    for (int mm = 0; mm < NH; mm += 4) {
#pragma unroll
        for (int u = 0; u < 4; ++u) {
            const int m = mm + u;
            const int slot = u;             // (mm+u)&3 == u (mm%4==0)
            const int wslot = (u + 3) & 3;  // ring slot for half m+3
            // tail: re-issue last half's (L2-hot) addresses into the dead
            // slot to keep vmcnt counts uniform
            const int kis = ((m + 3 < NH) ? (m + 3) : (NH - 1)) << 5;
            const short* la = &lds[slot * 16384 + aro];
            const short* lb = &lds[slot * 16384 + 8192 + bro];
            bf16x8 af[4], bfr[4];
            // ---- phase A: mi 0-3 ----
#pragma unroll
            for (int i = 0; i < 4; ++i)
                af[i] = *(const bf16x8*)(la + i * 512);
#pragma unroll
            for (int j = 0; j < 4; ++j)
                bfr[j] = *(const bf16x8*)(lb + j * 512);
            GLD16(agp + kis, lbase + wslot * 32768 + dst);
            GLD16(agp + kis + qstep, lbase + wslot * 32768 + 8192 + dst);
            __builtin_amdgcn_sched_barrier(0);
            __builtin_amdgcn_s_barrier();
            MFMA_CLUSTER(0);
            __builtin_amdgcn_s_barrier();
            // ---- phase B: mi 4-7 ----
#pragma unroll
            for (int i = 0; i < 4; ++i)
                af[i] = *(const bf16x8*)(la + (4 + i) * 512);
            GLD16(bgp + kis, lbase + wslot * 32768 + 16384 + dst);
            GLD16(bgp + kis + qstep, lbase + wslot * 32768 + 24576 + dst);
            __builtin_amdgcn_sched_barrier(0);
            __builtin_amdgcn_s_barrier();
            MFMA_CLUSTER(4);
            // retire half m+1 (issued 4-5 phases ago); keep 8 in flight
            asm volatile("s_waitcnt vmcnt(8)" ::: "memory");
            __builtin_amdgcn_s_barrier();
        }
    }

    // epilogue: ni-inner so each 4-row x 128B line group is written by
    // consecutive stores (write-combine friendly; round-1 order gave 1.73x
    // HBM write amplification)
    float bvv[4];
#pragma unroll
    for (int ni = 0; ni < 4; ++ni) bvv[ni] = bias[bn + wc * 64 + ni * 16 + fr];
#pragma unroll
    for (int mi = 0; mi < 8; ++mi) {
#pragma unroll
        for (int r = 0; r < 4; ++r) {
            const int row = bm + wr * 128 + mi * 16 + kq * 4 + r;
#pragma unroll
            for (int ni = 0; ni < 4; ++ni) {
                const int col = bn + wc * 64 + ni * 16 + fr;
                float v = acc[mi][ni][r] + bvv[ni];
                if (OUT_BF16)
                    ((short*)Cout)[(size_t)row * N + col] = f2b(v);
                else
                    ((float*)Cout)[(size_t)row * N + col] = v;
            }
        }
    }
    // drain tail garbage-stages before LDS dealloc at wave exit
    asm volatile("s_waitcnt vmcnt(0)" ::: "memory");
}

// ---- attention over heads axis, one wave per position ---------------------
__global__ __launch_bounds__(256) void attn_kernel(
    const short* __restrict__ Q, const short* __restrict__ KV,
    short* __restrict__ VAL) {
    const int wave = threadIdx.x >> 6;
    const int lane = threadIdx.x & 63;
    const size_t p = (size_t)blockIdx.x * 4 + wave;
    const int dq = lane & 3;

    const bf16x8* qp = (const bf16x8*)(Q + p * 1024 + (size_t)lane * 16);
    bf16x8 q0 = qp[0], q1 = qp[1];
    float q[16];
#pragma unroll
    for (int j = 0; j < 8; ++j) {
        q[j] = b2f(q0[j]);
        q[8 + j] = b2f(q1[j]);
    }

    const short* kvb = KV + p * 2048;

    float s[16];
#pragma unroll
    for (int g = 0; g < 16; ++g) {
        const bf16x8* kp = (const bf16x8*)(kvb + g * 128 + dq * 16);
        bf16x8 k0 = kp[0], k1 = kp[1];
        float d = 0.f;
#pragma unroll
        for (int j = 0; j < 8; ++j) {
            d += q[j] * b2f(k0[j]);
            d += q[8 + j] * b2f(k1[j]);
        }
        s[g] = d;
    }
    float mx = -1e30f;
#pragma unroll
    for (int g = 0; g < 16; ++g) {
        s[g] += __shfl_xor(s[g], 1, 64);
        s[g] += __shfl_xor(s[g], 2, 64);
        s[g] *= 0.125f;
        mx = fmaxf(mx, s[g]);
    }
    float ssum = 0.f;
#pragma unroll
    for (int g = 0; g < 16; ++g) {
        s[g] = __expf(s[g] - mx);
        ssum += s[g];
    }
    const float inv = 1.0f / ssum;

    float vo[16];
#pragma unroll
    for (int j = 0; j < 16; ++j) vo[j] = 0.f;
#pragma unroll
    for (int g = 0; g < 16; ++g) {
        const float w = s[g] * inv;
        const bf16x8* vp = (const bf16x8*)(kvb + g * 128 + 64 + dq * 16);
        bf16x8 v0 = vp[0], v1 = vp[1];
#pragma unroll
        for (int j = 0; j < 8; ++j) {
            vo[j] += w * b2f(v0[j]);
            vo[8 + j] += w * b2f(v1[j]);
        }
    }

    bf16x8 o0, o1;
#pragma unroll
    for (int j = 0; j < 8; ++j) {
        o0[j] = f2b(vo[j]);
        o1[j] = f2b(vo[8 + j]);
    }
    bf16x8* op = (bf16x8*)(VAL + p * 1024 + (size_t)lane * 16);
    op[0] = o0;
    op[1] = o1;
}

// ---------------------------------------------------------------------------
extern "C" void kernel_launch(void* const* d_in, const int* in_sizes, int n_in,
                              void* d_out, int out_size, void* d_ws,
                              size_t ws_size, hipStream_t stream) {
    const float* x = (const float*)d_in[0];
    const float* y = (const float*)d_in[1];
    const float* Wkv = (const float*)d_in[2];
    const float* bkv = (const float*)d_in[3];
    const float* Wq = (const float*)d_in[4];
    const float* bq = (const float*)d_in[5];
    const float* Wo = (const float*)d_in[6];
    const float* bo = (const float*)d_in[7];
    float* out = (float*)d_out;

    const int D = 1024;
    const int M = 16384;  // B*L

    // workspace layout (142.6 MB total)
    char* ws = (char*)d_ws;
    short* Xb = (short*)(ws);                      // M*D bf16      (33.5 MB)
    short* Yb = (short*)(ws + 33554432);           // M*D bf16      (33.5 MB)
    short* Wkvt = (short*)(ws + 67108864);         // 2D*D bf16     (4 MB)
    short* Wqt = (short*)(ws + 71303168);          // D*D bf16      (2 MB)
    short* Wot = (short*)(ws + 73400320);          // D*D bf16      (2 MB)
    short* KV = (short*)(ws + 75497472);           // M*2D bf16     (67 MB)
    short* Q = Xb;    // Xb dead after kv GEMM
    short* VAL = Yb;  // Yb dead after q GEMM

    const int n = M * D;  // 16777216

    cast2_f32_bf16<<<2 * n / 1024, 256, 0, stream>>>(x, Xb, y, Yb, n);
    transpose_cast2<<<dim3(2 * D / 32, D / 32, 1), dim3(32, 8), 0, stream>>>(
        Wkv, Wkvt, (const float*)0, (short*)0, D, 2 * D);
    transpose_cast2<<<dim3(D / 32, D / 32, 2), dim3(32, 8), 0, stream>>>(
        Wq, Wqt, Wo, Wot, D, D);

    // kv = x @ Wkv + bkv   [16384 x 2048] bf16
    gemm_bt<1><<<dim3(2 * D / BN, M / BM), 512, 0, stream>>>(
        Xb, Wkvt, bkv, KV, M, 2 * D, D);
    // q = y @ Wq + bq      [16384 x 1024] bf16 (into Xb slot)
    gemm_bt<1><<<dim3(D / BN, M / BM), 512, 0, stream>>>(
        Yb, Wqt, bq, Q, M, D, D);
    // attention over heads -> VAL (into Yb slot)
    attn_kernel<<<M / 4, 256, 0, stream>>>(Q, KV, VAL);
    // out = val @ Wo + bo  [16384 x 1024] fp32
    gemm_bt<0><<<dim3(D / BN, M / BM), 512, 0, stream>>>(
        VAL, Wot, bo, out, M, D, D);
}